// Round 2
// baseline (659.811 us; speedup 1.0000x reference)
//
#include <hip/hip_runtime.h>

#define DD 128

// deg counting: deg starts at 0 (memset); +1 per incoming edge; self-loop added in finish.
__global__ void k_count_deg(const int* __restrict__ dst, float* __restrict__ deg, int E) {
    int e = blockIdx.x * blockDim.x + threadIdx.x;
    if (e < E) atomicAdd(&deg[dst[e]], 1.0f);
}

// deg -> dis = rsqrt(deg + 1)   (the +1 is the self-loop)
__global__ void k_finish_deg(float* __restrict__ deg, int N) {
    int i = blockIdx.x * blockDim.x + threadIdx.x;
    if (i < N) deg[i] = rsqrtf(deg[i] + 1.0f);
}

// embW1[p][c] = sum_k emb[p][k] * W1[k][c]   (512 x 128 x 128 — tiny)
__global__ void k_emb_matmul(const float* __restrict__ emb,
                             const float* __restrict__ W,
                             float* __restrict__ out) {
    int p = blockIdx.x;       // 512
    int c = threadIdx.x;      // 128
    float s = 0.f;
#pragma unroll 8
    for (int k = 0; k < DD; k++)
        s += emb[p * DD + k] * W[k * DD + c];
    out[p * DD + c] = s;
}

// Layer-1 edge aggregation: one wave per edge, lane handles channels {lane, lane+64}.
// h1[src] == embW1[node_ids[src]] (double indirection into a 256KB cached table).
__global__ void k_agg_emb(const int* __restrict__ src, const int* __restrict__ dst,
                          const int* __restrict__ node_ids, const float* __restrict__ dis,
                          const float* __restrict__ embW, float* __restrict__ agg, int E) {
    long long gid = (long long)blockIdx.x * blockDim.x + threadIdx.x;
    int e = (int)(gid >> 6);
    int lane = (int)(gid & 63);
    if (e >= E) return;
    int s = src[e], d = dst[e];
    float norm = dis[s] * dis[d];
    const float* row = embW + (size_t)node_ids[s] * DD;
    float* outp = agg + (size_t)d * DD;
    atomicAdd(&outp[lane],      row[lane]      * norm);
    atomicAdd(&outp[lane + 64], row[lane + 64] * norm);
}

// Layer-2 edge aggregation: gather h2[src] directly.
__global__ void k_agg_h(const int* __restrict__ src, const int* __restrict__ dst,
                        const float* __restrict__ dis, const float* __restrict__ h,
                        float* __restrict__ agg, int E) {
    long long gid = (long long)blockIdx.x * blockDim.x + threadIdx.x;
    int e = (int)(gid >> 6);
    int lane = (int)(gid & 63);
    if (e >= E) return;
    int s = src[e], d = dst[e];
    float norm = dis[s] * dis[d];
    const float* row = h + (size_t)s * DD;
    float* outp = agg + (size_t)d * DD;
    atomicAdd(&outp[lane],      row[lane]      * norm);
    atomicAdd(&outp[lane + 64], row[lane + 64] * norm);
}

// Fused: self-loop term + bias + residual + LayerNorm (layer 1) -> x1 (fp32)
// One wave per node; lane owns channels {lane, lane+64}; shuffle reductions.
__global__ void k_ln1(const int* __restrict__ node_ids, const float* __restrict__ emb,
                      const float* __restrict__ embW1, const float* __restrict__ dis,
                      const float* __restrict__ agg,
                      const float* __restrict__ b1,
                      const float* __restrict__ g1,
                      const float* __restrict__ beta1,
                      float* __restrict__ x1, int N) {
    long long gid = (long long)blockIdx.x * blockDim.x + threadIdx.x;
    int i = (int)(gid >> 6);
    int lane = (int)(gid & 63);
    if (i >= N) return;
    int p = node_ids[i];
    float sn = dis[i] * dis[i];
    int c0 = lane, c1 = lane + 64;
    size_t pb = (size_t)p * DD;
    size_t ib = (size_t)i * DD;
    float v0 = emb[pb + c0] + agg[ib + c0] + embW1[pb + c0] * sn + b1[c0];
    float v1 = emb[pb + c1] + agg[ib + c1] + embW1[pb + c1] * sn + b1[c1];
    float sum = v0 + v1;
#pragma unroll
    for (int o = 32; o >= 1; o >>= 1) sum += __shfl_xor(sum, o, 64);
    float mu = sum * (1.f / DD);
    float d0 = v0 - mu, d1 = v1 - mu;
    float ss = d0 * d0 + d1 * d1;
#pragma unroll
    for (int o = 32; o >= 1; o >>= 1) ss += __shfl_xor(ss, o, 64);
    float r = rsqrtf(ss * (1.f / DD) + 1e-5f);
    x1[ib + c0] = d0 * r * g1[c0] + beta1[c0];
    x1[ib + c1] = d1 * r * g1[c1] + beta1[c1];
}

// h2 = x1 @ W2.  W2 (fp32, 64KB) staged in LDS as [k][c]; thread computes 4 cols via float4.
__global__ __launch_bounds__(256) void k_gemm(const float* __restrict__ x,
                                              const float* __restrict__ W,
                                              float* __restrict__ h, int N) {
    __shared__ float Ws[DD * DD];  // exactly 64 KB
    for (int t = threadIdx.x; t < DD * DD; t += 256) Ws[t] = W[t];
    __syncthreads();
    int lr = threadIdx.x >> 5;          // 0..7: local row
    int c4 = (threadIdx.x & 31) * 4;    // col group
    for (int r0 = blockIdx.x * 8; r0 < N; r0 += gridDim.x * 8) {
        int row = r0 + lr;
        if (row < N) {
            const float* xr = x + (size_t)row * DD;
            float4 acc = make_float4(0.f, 0.f, 0.f, 0.f);
#pragma unroll 4
            for (int k = 0; k < DD; k++) {
                float xk = xr[k];
                float4 w = *(const float4*)&Ws[k * DD + c4];
                acc.x = fmaf(xk, w.x, acc.x);
                acc.y = fmaf(xk, w.y, acc.y);
                acc.z = fmaf(xk, w.z, acc.z);
                acc.w = fmaf(xk, w.w, acc.w);
            }
            *(float4*)(h + (size_t)row * DD + c4) = acc;
        }
    }
}

// Fused: self-loop + bias + residual + LayerNorm (layer 2) -> fp32 output
__global__ void k_ln2(const float* __restrict__ x1, const float* __restrict__ agg,
                      const float* __restrict__ h2, const float* __restrict__ dis,
                      const float* __restrict__ b2,
                      const float* __restrict__ g2,
                      const float* __restrict__ beta2,
                      float* __restrict__ out, int N) {
    long long gid = (long long)blockIdx.x * blockDim.x + threadIdx.x;
    int i = (int)(gid >> 6);
    int lane = (int)(gid & 63);
    if (i >= N) return;
    float sn = dis[i] * dis[i];
    int c0 = lane, c1 = lane + 64;
    size_t ib = (size_t)i * DD;
    float v0 = x1[ib + c0] + agg[ib + c0] + h2[ib + c0] * sn + b2[c0];
    float v1 = x1[ib + c1] + agg[ib + c1] + h2[ib + c1] * sn + b2[c1];
    float sum = v0 + v1;
#pragma unroll
    for (int o = 32; o >= 1; o >>= 1) sum += __shfl_xor(sum, o, 64);
    float mu = sum * (1.f / DD);
    float d0 = v0 - mu, d1 = v1 - mu;
    float ss = d0 * d0 + d1 * d1;
#pragma unroll
    for (int o = 32; o >= 1; o >>= 1) ss += __shfl_xor(ss, o, 64);
    float r = rsqrtf(ss * (1.f / DD) + 1e-5f);
    out[ib + c0] = d0 * r * g2[c0] + beta2[c0];
    out[ib + c1] = d1 * r * g2[c1] + beta2[c1];
}

extern "C" void kernel_launch(void* const* d_in, const int* in_sizes, int n_in,
                              void* d_out, int out_size, void* d_ws, size_t ws_size,
                              hipStream_t stream) {
    const int* node_ids = (const int*)d_in[0];
    const int* edge_index = (const int*)d_in[1];
    const float* emb   = (const float*)d_in[2];
    const float* W1    = (const float*)d_in[3];
    const float* b1    = (const float*)d_in[4];
    const float* W2    = (const float*)d_in[5];
    const float* b2    = (const float*)d_in[6];
    const float* g1    = (const float*)d_in[7];
    const float* beta1 = (const float*)d_in[8];
    const float* g2    = (const float*)d_in[9];
    const float* beta2 = (const float*)d_in[10];
    const int N = in_sizes[0];
    const int E = in_sizes[1] / 2;
    const int* src  = edge_index;       // edge_index[0, :]
    const int* dstp = edge_index + E;   // edge_index[1, :]
    float* out = (float*)d_out;

    // workspace carve-out (all fp32): dis[N], embW1[512*128], agg[N*128], x1[N*128], h2[N*128]
    char* base = (char*)d_ws;
    size_t off = 0;
    auto carve = [&](size_t bytes) -> void* {
        void* p = base + off;
        off += (bytes + 255) & ~(size_t)255;
        return p;
    };
    float* dis   = (float*)carve((size_t)N * 4);
    float* embW1 = (float*)carve((size_t)512 * DD * 4);
    float* agg   = (float*)carve((size_t)N * DD * 4);
    float* x1    = (float*)carve((size_t)N * DD * 4);
    float* h2    = (float*)carve((size_t)N * DD * 4);
    (void)ws_size; (void)n_in; (void)out_size;

    const int TB = 256;
    hipMemsetAsync(dis, 0, (size_t)N * 4, stream);
    hipMemsetAsync(agg, 0, (size_t)N * DD * 4, stream);

    k_count_deg<<<(E + TB - 1) / TB, TB, 0, stream>>>(dstp, dis, E);
    k_finish_deg<<<(N + TB - 1) / TB, TB, 0, stream>>>(dis, N);
    k_emb_matmul<<<512, DD, 0, stream>>>(emb, W1, embW1);

    long long te = (long long)E * 64;
    long long tn = (long long)N * 64;
    k_agg_emb<<<(unsigned)((te + TB - 1) / TB), TB, 0, stream>>>(src, dstp, node_ids, dis, embW1, agg, E);
    k_ln1<<<(unsigned)((tn + TB - 1) / TB), TB, 0, stream>>>(node_ids, emb, embW1, dis, agg, b1, g1, beta1, x1, N);

    hipMemsetAsync(agg, 0, (size_t)N * DD * 4, stream);
    k_gemm<<<2048, 256, 0, stream>>>(x1, W2, h2, N);
    k_agg_h<<<(unsigned)((te + TB - 1) / TB), TB, 0, stream>>>(src, dstp, dis, h2, agg, E);
    k_ln2<<<(unsigned)((tn + TB - 1) / TB), TB, 0, stream>>>(x1, agg, h2, dis, b2, g2, beta2, out, N);
}

// Round 3
// 446.520 us; speedup vs baseline: 1.4777x; 1.4777x over previous
//
#include <hip/hip_runtime.h>

#define DD 128

// ---- in-degree histogram (int) ----
__global__ void k_hist(const int* __restrict__ dst, int* __restrict__ cnt, int E) {
    int e = blockIdx.x * blockDim.x + threadIdx.x;
    if (e < E) atomicAdd(&cnt[dst[e]], 1);
}

// ---- single-block scan: cnt -> rowptr/cursor (exclusive), dis = rsqrt(cnt+1) ----
__global__ __launch_bounds__(1024) void k_scan(const int* __restrict__ cnt,
                                               int* __restrict__ rowptr,
                                               int* __restrict__ cursor,
                                               float* __restrict__ dis, int N, int E) {
    __shared__ int sums[1024];
    int t = threadIdx.x;
    int chunk = (N + 1023) >> 10;
    int beg = t * chunk; if (beg > N) beg = N;
    int end = beg + chunk; if (end > N) end = N;
    int s = 0;
    for (int i = beg; i < end; i++) s += cnt[i];
    sums[t] = s;
    __syncthreads();
    for (int off = 1; off < 1024; off <<= 1) {
        int v = (t >= off) ? sums[t - off] : 0;
        __syncthreads();
        sums[t] += v;
        __syncthreads();
    }
    int o = sums[t] - s;  // exclusive prefix
    for (int i = beg; i < end; i++) {
        rowptr[i] = o; cursor[i] = o; o += cnt[i];
        dis[i] = rsqrtf((float)cnt[i] + 1.0f);
    }
    if (t == 1023) rowptr[N] = E;
}

// ---- embW1[p][c] = (emb @ W1)[p][c]   (512 x 128 x 128 — tiny) ----
__global__ void k_emb_matmul(const float* __restrict__ emb,
                             const float* __restrict__ W,
                             float* __restrict__ out) {
    int p = blockIdx.x;
    int c = threadIdx.x;
    float s = 0.f;
#pragma unroll 8
    for (int k = 0; k < DD; k++)
        s += emb[p * DD + k] * W[k * DD + c];
    out[p * DD + c] = s;
}

// ---- bucket edges by dst: per-edge streams srcs / widx / disv ----
__global__ void k_bucket(const int* __restrict__ src, const int* __restrict__ dst,
                         const int* __restrict__ node_ids, const float* __restrict__ dis,
                         int* __restrict__ cursor, int* __restrict__ srcs,
                         int* __restrict__ widx, float* __restrict__ disv, int E) {
    int e = blockIdx.x * blockDim.x + threadIdx.x;
    if (e >= E) return;
    int s = src[e], d = dst[e];
    int pos = atomicAdd(&cursor[d], 1);
    srcs[pos] = s;
    widx[pos] = node_ids[s];
    disv[pos] = dis[s];
}

// ---- layer 1 fused: gather-reduce from embW1 table + self-loop + bias + residual + LN -> x1
// one wave per node; lane owns channels {2*lane, 2*lane+1} (float2, 512B/row coalesced)
__global__ __launch_bounds__(256) void k_node1(const int* __restrict__ rowptr,
                                               const int* __restrict__ widx,
                                               const float* __restrict__ disv,
                                               const int* __restrict__ node_ids,
                                               const float* __restrict__ emb,
                                               const float* __restrict__ embW1,
                                               const float* __restrict__ dis,
                                               const float* __restrict__ b1,
                                               const float* __restrict__ g1,
                                               const float* __restrict__ beta1,
                                               float* __restrict__ x1, int N) {
    int i = (blockIdx.x * blockDim.x + threadIdx.x) >> 6;
    int lane = threadIdx.x & 63;
    if (i >= N) return;
    int r0 = rowptr[i], r1 = rowptr[i + 1];
    int c = lane * 2;
    float ax = 0.f, ay = 0.f;
    int j = r0;
    for (; j + 1 < r1; j += 2) {
        int p0 = widx[j], p1 = widx[j + 1];
        float n0 = disv[j], n1 = disv[j + 1];
        float2 a0 = *(const float2*)(embW1 + (size_t)p0 * DD + c);
        float2 a1 = *(const float2*)(embW1 + (size_t)p1 * DD + c);
        ax += a0.x * n0 + a1.x * n1;
        ay += a0.y * n0 + a1.y * n1;
    }
    if (j < r1) {
        int p = widx[j]; float n = disv[j];
        float2 a = *(const float2*)(embW1 + (size_t)p * DD + c);
        ax += a.x * n; ay += a.y * n;
    }
    float di = dis[i];
    int pid = node_ids[i];
    float2 ev = *(const float2*)(emb + (size_t)pid * DD + c);
    float2 hw = *(const float2*)(embW1 + (size_t)pid * DD + c);
    float v0 = ev.x + di * (ax + di * hw.x) + b1[c];
    float v1 = ev.y + di * (ay + di * hw.y) + b1[c + 1];
    float sum = v0 + v1;
#pragma unroll
    for (int o = 32; o >= 1; o >>= 1) sum += __shfl_xor(sum, o, 64);
    float mu = sum * (1.f / DD);
    float d0 = v0 - mu, d1 = v1 - mu;
    float ss = d0 * d0 + d1 * d1;
#pragma unroll
    for (int o = 32; o >= 1; o >>= 1) ss += __shfl_xor(ss, o, 64);
    float r = rsqrtf(ss * (1.f / DD) + 1e-5f);
    float2 outv;
    outv.x = d0 * r * g1[c] + beta1[c];
    outv.y = d1 * r * g1[c + 1] + beta1[c + 1];
    *(float2*)(x1 + (size_t)i * DD + c) = outv;
}

// ---- h2s = (x1 @ W2) * dis[row]  (row pre-scaled by dis[src] for layer-2 aggregation) ----
__global__ __launch_bounds__(256) void k_gemm(const float* __restrict__ x,
                                              const float* __restrict__ W,
                                              const float* __restrict__ dis,
                                              float* __restrict__ h, int N) {
    __shared__ float Ws[DD * DD];  // 64 KB
    for (int t = threadIdx.x; t < DD * DD; t += 256) Ws[t] = W[t];
    __syncthreads();
    int lr = threadIdx.x >> 5;
    int c4 = (threadIdx.x & 31) * 4;
    for (int r0 = blockIdx.x * 8; r0 < N; r0 += gridDim.x * 8) {
        int row = r0 + lr;
        if (row < N) {
            const float* xr = x + (size_t)row * DD;
            float4 acc = make_float4(0.f, 0.f, 0.f, 0.f);
#pragma unroll 4
            for (int k = 0; k < DD; k++) {
                float xk = xr[k];
                float4 w = *(const float4*)&Ws[k * DD + c4];
                acc.x = fmaf(xk, w.x, acc.x);
                acc.y = fmaf(xk, w.y, acc.y);
                acc.z = fmaf(xk, w.z, acc.z);
                acc.w = fmaf(xk, w.w, acc.w);
            }
            float ds = dis[row];
            acc.x *= ds; acc.y *= ds; acc.z *= ds; acc.w *= ds;
            *(float4*)(h + (size_t)row * DD + c4) = acc;
        }
    }
}

// ---- layer 2 fused: gather-reduce of pre-scaled h2s rows + self-loop + bias + residual + LN -> out
__global__ __launch_bounds__(256) void k_node2(const int* __restrict__ rowptr,
                                               const int* __restrict__ srcs,
                                               const float* __restrict__ x1,
                                               const float* __restrict__ h2s,
                                               const float* __restrict__ dis,
                                               const float* __restrict__ b2,
                                               const float* __restrict__ g2,
                                               const float* __restrict__ beta2,
                                               float* __restrict__ out, int N) {
    int i = (blockIdx.x * blockDim.x + threadIdx.x) >> 6;
    int lane = threadIdx.x & 63;
    if (i >= N) return;
    int r0 = rowptr[i], r1 = rowptr[i + 1];
    int c = lane * 2;
    float ax = 0.f, ay = 0.f;
    int j = r0;
    for (; j + 1 < r1; j += 2) {
        int s0 = srcs[j], s1 = srcs[j + 1];
        float2 a0 = *(const float2*)(h2s + (size_t)s0 * DD + c);
        float2 a1 = *(const float2*)(h2s + (size_t)s1 * DD + c);
        ax += a0.x + a1.x;
        ay += a0.y + a1.y;
    }
    if (j < r1) {
        int s = srcs[j];
        float2 a = *(const float2*)(h2s + (size_t)s * DD + c);
        ax += a.x; ay += a.y;
    }
    float di = dis[i];
    size_t ib = (size_t)i * DD + c;
    float2 xv = *(const float2*)(x1 + ib);
    float2 hv = *(const float2*)(h2s + ib);  // already scaled by dis[i]
    float v0 = xv.x + di * (ax + hv.x) + b2[c];
    float v1 = xv.y + di * (ay + hv.y) + b2[c + 1];
    float sum = v0 + v1;
#pragma unroll
    for (int o = 32; o >= 1; o >>= 1) sum += __shfl_xor(sum, o, 64);
    float mu = sum * (1.f / DD);
    float d0 = v0 - mu, d1 = v1 - mu;
    float ss = d0 * d0 + d1 * d1;
#pragma unroll
    for (int o = 32; o >= 1; o >>= 1) ss += __shfl_xor(ss, o, 64);
    float r = rsqrtf(ss * (1.f / DD) + 1e-5f);
    float2 outv;
    outv.x = d0 * r * g2[c] + beta2[c];
    outv.y = d1 * r * g2[c + 1] + beta2[c + 1];
    *(float2*)(out + ib) = outv;
}

extern "C" void kernel_launch(void* const* d_in, const int* in_sizes, int n_in,
                              void* d_out, int out_size, void* d_ws, size_t ws_size,
                              hipStream_t stream) {
    const int* node_ids = (const int*)d_in[0];
    const int* edge_index = (const int*)d_in[1];
    const float* emb   = (const float*)d_in[2];
    const float* W1    = (const float*)d_in[3];
    const float* b1    = (const float*)d_in[4];
    const float* W2    = (const float*)d_in[5];
    const float* b2    = (const float*)d_in[6];
    const float* g1    = (const float*)d_in[7];
    const float* beta1 = (const float*)d_in[8];
    const float* g2    = (const float*)d_in[9];
    const float* beta2 = (const float*)d_in[10];
    const int N = in_sizes[0];
    const int E = in_sizes[1] / 2;
    const int* srcp = edge_index;       // edge_index[0, :]
    const int* dstp = edge_index + E;   // edge_index[1, :]
    float* out = (float*)d_out;

    char* base = (char*)d_ws;
    size_t off = 0;
    auto carve = [&](size_t bytes) -> void* {
        void* p = base + off;
        off += (bytes + 255) & ~(size_t)255;
        return p;
    };
    int*   cnt    = (int*)carve((size_t)N * 4);
    int*   rowptr = (int*)carve((size_t)(N + 1) * 4);
    int*   cursor = (int*)carve((size_t)N * 4);
    float* dis    = (float*)carve((size_t)N * 4);
    int*   srcs   = (int*)carve((size_t)E * 4);
    int*   widx   = (int*)carve((size_t)E * 4);
    float* disv   = (float*)carve((size_t)E * 4);
    float* embW1  = (float*)carve((size_t)512 * DD * 4);
    float* x1     = (float*)carve((size_t)N * DD * 4);
    float* h2s    = (float*)carve((size_t)N * DD * 4);
    (void)ws_size; (void)n_in; (void)out_size;

    const int TB = 256;
    hipMemsetAsync(cnt, 0, (size_t)N * 4, stream);

    k_hist<<<(E + TB - 1) / TB, TB, 0, stream>>>(dstp, cnt, E);
    k_scan<<<1, 1024, 0, stream>>>(cnt, rowptr, cursor, dis, N, E);
    k_emb_matmul<<<512, DD, 0, stream>>>(emb, W1, embW1);
    k_bucket<<<(E + TB - 1) / TB, TB, 0, stream>>>(srcp, dstp, node_ids, dis, cursor,
                                                   srcs, widx, disv, E);

    int nodeBlocks = (N * 64 + TB - 1) / TB;
    k_node1<<<nodeBlocks, TB, 0, stream>>>(rowptr, widx, disv, node_ids, emb, embW1, dis,
                                           b1, g1, beta1, x1, N);
    k_gemm<<<2048, 256, 0, stream>>>(x1, W2, dis, h2s, N);
    k_node2<<<nodeBlocks, TB, 0, stream>>>(rowptr, srcs, x1, h2s, dis,
                                           b2, g2, beta2, out, N);
}

// Round 4
// 318.070 us; speedup vs baseline: 2.0744x; 1.4038x over previous
//
#include <hip/hip_runtime.h>

#define DD 128

// ---- in-degree histogram (int) ----
__global__ void k_hist(const int* __restrict__ dst, int* __restrict__ cnt, int E) {
    int e = blockIdx.x * blockDim.x + threadIdx.x;
    if (e < E) atomicAdd(&cnt[dst[e]], 1);
}

// ---- scan phase 1: per-block (1024-elem tile) exclusive prefix + block totals + dis ----
__global__ __launch_bounds__(256) void k_scan1(const int* __restrict__ cnt,
                                               int* __restrict__ rowptr,
                                               float* __restrict__ dis,
                                               int* __restrict__ bsum, int N) {
    __shared__ int sums[256];
    int t = threadIdx.x;
    int base = blockIdx.x * 1024 + t * 4;
    int c0 = 0, c1 = 0, c2 = 0, c3 = 0;
    if (base + 3 < N) {
        const int4 v = *(const int4*)(cnt + base);
        c0 = v.x; c1 = v.y; c2 = v.z; c3 = v.w;
    } else {
        if (base + 0 < N) c0 = cnt[base + 0];
        if (base + 1 < N) c1 = cnt[base + 1];
        if (base + 2 < N) c2 = cnt[base + 2];
        if (base + 3 < N) c3 = cnt[base + 3];
    }
    int ts = c0 + c1 + c2 + c3;
    sums[t] = ts;
    __syncthreads();
    for (int off = 1; off < 256; off <<= 1) {
        int v = (t >= off) ? sums[t - off] : 0;
        __syncthreads();
        sums[t] += v;
        __syncthreads();
    }
    int pre = sums[t] - ts;  // exclusive prefix within block
    if (base + 0 < N) { rowptr[base + 0] = pre;                 dis[base + 0] = rsqrtf((float)c0 + 1.f); }
    if (base + 1 < N) { rowptr[base + 1] = pre + c0;            dis[base + 1] = rsqrtf((float)c1 + 1.f); }
    if (base + 2 < N) { rowptr[base + 2] = pre + c0 + c1;       dis[base + 2] = rsqrtf((float)c2 + 1.f); }
    if (base + 3 < N) { rowptr[base + 3] = pre + c0 + c1 + c2;  dis[base + 3] = rsqrtf((float)c3 + 1.f); }
    if (t == 255) bsum[blockIdx.x] = sums[255];
}

// ---- scan phase 2: exclusive prefix of block totals (B <= 256) ----
__global__ __launch_bounds__(256) void k_scan2(int* __restrict__ bsum, int B) {
    __shared__ int s[256];
    int t = threadIdx.x;
    int v = (t < B) ? bsum[t] : 0;
    s[t] = v;
    __syncthreads();
    for (int off = 1; off < 256; off <<= 1) {
        int u = (t >= off) ? s[t - off] : 0;
        __syncthreads();
        s[t] += u;
        __syncthreads();
    }
    if (t < B) bsum[t] = s[t] - v;  // exclusive
}

// ---- scan phase 3: add block offsets; materialize cursor; rowptr[N]=E ----
__global__ __launch_bounds__(256) void k_scan3(int* __restrict__ rowptr,
                                               int* __restrict__ cursor,
                                               const int* __restrict__ bsum, int N, int E) {
    int i = blockIdx.x * blockDim.x + threadIdx.x;
    if (i < N) {
        int v = rowptr[i] + bsum[i >> 10];
        rowptr[i] = v;
        cursor[i] = v;
    }
    if (i == 0) rowptr[N] = E;
}

// ---- embW1[p][c] = (emb @ W1)[p][c]   (512 x 128 x 128 — tiny) ----
__global__ void k_emb_matmul(const float* __restrict__ emb,
                             const float* __restrict__ W,
                             float* __restrict__ out) {
    int p = blockIdx.x;
    int c = threadIdx.x;
    float s = 0.f;
#pragma unroll 8
    for (int k = 0; k < DD; k++)
        s += emb[p * DD + k] * W[k * DD + c];
    out[p * DD + c] = s;
}

// ---- bucket edges by dst: per-edge streams srcs / widx / disv ----
__global__ void k_bucket(const int* __restrict__ src, const int* __restrict__ dst,
                         const int* __restrict__ node_ids, const float* __restrict__ dis,
                         int* __restrict__ cursor, int* __restrict__ srcs,
                         int* __restrict__ widx, float* __restrict__ disv, int E) {
    int e = blockIdx.x * blockDim.x + threadIdx.x;
    if (e >= E) return;
    int s = src[e], d = dst[e];
    int pos = atomicAdd(&cursor[d], 1);
    srcs[pos] = s;
    widx[pos] = node_ids[s];
    disv[pos] = dis[s];
}

// ---- layer 1 fused: gather-reduce from embW1 table + self-loop + bias + residual + LN -> x1
// one wave per node; lane owns channels {2*lane, 2*lane+1}; 4-wide edge unroll for MLP
__global__ __launch_bounds__(256) void k_node1(const int* __restrict__ rowptr,
                                               const int* __restrict__ widx,
                                               const float* __restrict__ disv,
                                               const int* __restrict__ node_ids,
                                               const float* __restrict__ emb,
                                               const float* __restrict__ embW1,
                                               const float* __restrict__ dis,
                                               const float* __restrict__ b1,
                                               const float* __restrict__ g1,
                                               const float* __restrict__ beta1,
                                               float* __restrict__ x1, int N) {
    int i = (blockIdx.x * blockDim.x + threadIdx.x) >> 6;
    int lane = threadIdx.x & 63;
    if (i >= N) return;
    int r0 = rowptr[i], r1 = rowptr[i + 1];
    int c = lane * 2;
    float ax = 0.f, ay = 0.f;
    int j = r0;
    for (; j + 3 < r1; j += 4) {
        int p0 = widx[j], p1 = widx[j + 1], p2 = widx[j + 2], p3 = widx[j + 3];
        float n0 = disv[j], n1 = disv[j + 1], n2 = disv[j + 2], n3 = disv[j + 3];
        float2 a0 = *(const float2*)(embW1 + (size_t)p0 * DD + c);
        float2 a1 = *(const float2*)(embW1 + (size_t)p1 * DD + c);
        float2 a2 = *(const float2*)(embW1 + (size_t)p2 * DD + c);
        float2 a3 = *(const float2*)(embW1 + (size_t)p3 * DD + c);
        ax += a0.x * n0 + a1.x * n1 + a2.x * n2 + a3.x * n3;
        ay += a0.y * n0 + a1.y * n1 + a2.y * n2 + a3.y * n3;
    }
    for (; j < r1; j++) {
        int p = widx[j]; float n = disv[j];
        float2 a = *(const float2*)(embW1 + (size_t)p * DD + c);
        ax += a.x * n; ay += a.y * n;
    }
    float di = dis[i];
    int pid = node_ids[i];
    float2 ev = *(const float2*)(emb + (size_t)pid * DD + c);
    float2 hw = *(const float2*)(embW1 + (size_t)pid * DD + c);
    float v0 = ev.x + di * (ax + di * hw.x) + b1[c];
    float v1 = ev.y + di * (ay + di * hw.y) + b1[c + 1];
    float sum = v0 + v1;
#pragma unroll
    for (int o = 32; o >= 1; o >>= 1) sum += __shfl_xor(sum, o, 64);
    float mu = sum * (1.f / DD);
    float d0 = v0 - mu, d1 = v1 - mu;
    float ss = d0 * d0 + d1 * d1;
#pragma unroll
    for (int o = 32; o >= 1; o >>= 1) ss += __shfl_xor(ss, o, 64);
    float r = rsqrtf(ss * (1.f / DD) + 1e-5f);
    float2 outv;
    outv.x = d0 * r * g1[c] + beta1[c];
    outv.y = d1 * r * g1[c + 1] + beta1[c + 1];
    *(float2*)(x1 + (size_t)i * DD + c) = outv;
}

// ---- h2s = (x1 @ W2) * dis[row]  (row pre-scaled by dis[src] for layer-2 aggregation) ----
__global__ __launch_bounds__(256) void k_gemm(const float* __restrict__ x,
                                              const float* __restrict__ W,
                                              const float* __restrict__ dis,
                                              float* __restrict__ h, int N) {
    __shared__ float Ws[DD * DD];  // 64 KB
    for (int t = threadIdx.x; t < DD * DD; t += 256) Ws[t] = W[t];
    __syncthreads();
    int lr = threadIdx.x >> 5;
    int c4 = (threadIdx.x & 31) * 4;
    for (int r0 = blockIdx.x * 8; r0 < N; r0 += gridDim.x * 8) {
        int row = r0 + lr;
        if (row < N) {
            const float* xr = x + (size_t)row * DD;
            float4 acc = make_float4(0.f, 0.f, 0.f, 0.f);
#pragma unroll 4
            for (int k = 0; k < DD; k++) {
                float xk = xr[k];
                float4 w = *(const float4*)&Ws[k * DD + c4];
                acc.x = fmaf(xk, w.x, acc.x);
                acc.y = fmaf(xk, w.y, acc.y);
                acc.z = fmaf(xk, w.z, acc.z);
                acc.w = fmaf(xk, w.w, acc.w);
            }
            float ds = dis[row];
            acc.x *= ds; acc.y *= ds; acc.z *= ds; acc.w *= ds;
            *(float4*)(h + (size_t)row * DD + c4) = acc;
        }
    }
}

// ---- layer 2 fused: gather-reduce of pre-scaled h2s rows + self-loop + bias + residual + LN -> out
__global__ __launch_bounds__(256) void k_node2(const int* __restrict__ rowptr,
                                               const int* __restrict__ srcs,
                                               const float* __restrict__ x1,
                                               const float* __restrict__ h2s,
                                               const float* __restrict__ dis,
                                               const float* __restrict__ b2,
                                               const float* __restrict__ g2,
                                               const float* __restrict__ beta2,
                                               float* __restrict__ out, int N) {
    int i = (blockIdx.x * blockDim.x + threadIdx.x) >> 6;
    int lane = threadIdx.x & 63;
    if (i >= N) return;
    int r0 = rowptr[i], r1 = rowptr[i + 1];
    int c = lane * 2;
    float ax = 0.f, ay = 0.f;
    int j = r0;
    for (; j + 3 < r1; j += 4) {
        int s0 = srcs[j], s1 = srcs[j + 1], s2 = srcs[j + 2], s3 = srcs[j + 3];
        float2 a0 = *(const float2*)(h2s + (size_t)s0 * DD + c);
        float2 a1 = *(const float2*)(h2s + (size_t)s1 * DD + c);
        float2 a2 = *(const float2*)(h2s + (size_t)s2 * DD + c);
        float2 a3 = *(const float2*)(h2s + (size_t)s3 * DD + c);
        ax += a0.x + a1.x + a2.x + a3.x;
        ay += a0.y + a1.y + a2.y + a3.y;
    }
    for (; j < r1; j++) {
        int s = srcs[j];
        float2 a = *(const float2*)(h2s + (size_t)s * DD + c);
        ax += a.x; ay += a.y;
    }
    float di = dis[i];
    size_t ib = (size_t)i * DD + c;
    float2 xv = *(const float2*)(x1 + ib);
    float2 hv = *(const float2*)(h2s + ib);  // already scaled by dis[i]
    float v0 = xv.x + di * (ax + hv.x) + b2[c];
    float v1 = xv.y + di * (ay + hv.y) + b2[c + 1];
    float sum = v0 + v1;
#pragma unroll
    for (int o = 32; o >= 1; o >>= 1) sum += __shfl_xor(sum, o, 64);
    float mu = sum * (1.f / DD);
    float d0 = v0 - mu, d1 = v1 - mu;
    float ss = d0 * d0 + d1 * d1;
#pragma unroll
    for (int o = 32; o >= 1; o >>= 1) ss += __shfl_xor(ss, o, 64);
    float r = rsqrtf(ss * (1.f / DD) + 1e-5f);
    float2 outv;
    outv.x = d0 * r * g2[c] + beta2[c];
    outv.y = d1 * r * g2[c + 1] + beta2[c + 1];
    *(float2*)(out + ib) = outv;
}

extern "C" void kernel_launch(void* const* d_in, const int* in_sizes, int n_in,
                              void* d_out, int out_size, void* d_ws, size_t ws_size,
                              hipStream_t stream) {
    const int* node_ids = (const int*)d_in[0];
    const int* edge_index = (const int*)d_in[1];
    const float* emb   = (const float*)d_in[2];
    const float* W1    = (const float*)d_in[3];
    const float* b1    = (const float*)d_in[4];
    const float* W2    = (const float*)d_in[5];
    const float* b2    = (const float*)d_in[6];
    const float* g1    = (const float*)d_in[7];
    const float* beta1 = (const float*)d_in[8];
    const float* g2    = (const float*)d_in[9];
    const float* beta2 = (const float*)d_in[10];
    const int N = in_sizes[0];
    const int E = in_sizes[1] / 2;
    const int* srcp = edge_index;       // edge_index[0, :]
    const int* dstp = edge_index + E;   // edge_index[1, :]
    float* out = (float*)d_out;

    char* base = (char*)d_ws;
    size_t off = 0;
    auto carve = [&](size_t bytes) -> void* {
        void* p = base + off;
        off += (bytes + 255) & ~(size_t)255;
        return p;
    };
    int*   cnt    = (int*)carve((size_t)N * 4);
    int*   rowptr = (int*)carve((size_t)(N + 1) * 4);
    int*   cursor = (int*)carve((size_t)N * 4);
    float* dis    = (float*)carve((size_t)N * 4);
    int*   bsum   = (int*)carve((size_t)256 * 4);
    int*   srcs   = (int*)carve((size_t)E * 4);
    int*   widx   = (int*)carve((size_t)E * 4);
    float* disv   = (float*)carve((size_t)E * 4);
    float* embW1  = (float*)carve((size_t)512 * DD * 4);
    float* x1     = (float*)carve((size_t)N * DD * 4);
    float* h2s    = (float*)carve((size_t)N * DD * 4);
    (void)ws_size; (void)n_in; (void)out_size;

    const int TB = 256;
    const int B = (N + 1023) / 1024;  // scan blocks (49 for N=50000)
    hipMemsetAsync(cnt, 0, (size_t)N * 4, stream);

    k_hist<<<(E + TB - 1) / TB, TB, 0, stream>>>(dstp, cnt, E);
    k_scan1<<<B, 256, 0, stream>>>(cnt, rowptr, dis, bsum, N);
    k_scan2<<<1, 256, 0, stream>>>(bsum, B);
    k_scan3<<<(N + TB - 1) / TB, TB, 0, stream>>>(rowptr, cursor, bsum, N, E);
    k_emb_matmul<<<512, DD, 0, stream>>>(emb, W1, embW1);
    k_bucket<<<(E + TB - 1) / TB, TB, 0, stream>>>(srcp, dstp, node_ids, dis, cursor,
                                                   srcs, widx, disv, E);

    int nodeBlocks = (N * 64 + TB - 1) / TB;
    k_node1<<<nodeBlocks, TB, 0, stream>>>(rowptr, widx, disv, node_ids, emb, embW1, dis,
                                           b1, g1, beta1, x1, N);
    k_gemm<<<2048, 256, 0, stream>>>(x1, W2, dis, h2s, N);
    k_node2<<<nodeBlocks, TB, 0, stream>>>(rowptr, srcs, x1, h2s, dis,
                                           b2, g2, beta2, out, N);
}

// Round 5
// 248.277 us; speedup vs baseline: 2.6576x; 1.2811x over previous
//
#include <hip/hip_runtime.h>

#define DD 128

typedef __attribute__((ext_vector_type(8))) short short8;
typedef __attribute__((ext_vector_type(4))) float float4v;

static __device__ __forceinline__ unsigned short f2bf(float x) {
    unsigned u = __builtin_bit_cast(unsigned, x);
    u += 0x7fffu + ((u >> 16) & 1u);   // RNE
    return (unsigned short)(u >> 16);
}

// ---- in-degree histogram (int) ----
__global__ void k_hist(const int* __restrict__ dst, int* __restrict__ cnt, int E) {
    int e = blockIdx.x * blockDim.x + threadIdx.x;
    if (e < E) atomicAdd(&cnt[dst[e]], 1);
}

// ---- scan phase 1: per-block (1024-elem tile) exclusive prefix + block totals + dis ----
__global__ __launch_bounds__(256) void k_scan1(const int* __restrict__ cnt,
                                               int* __restrict__ rowptr,
                                               float* __restrict__ dis,
                                               int* __restrict__ bsum, int N) {
    __shared__ int sums[256];
    int t = threadIdx.x;
    int base = blockIdx.x * 1024 + t * 4;
    int c0 = 0, c1 = 0, c2 = 0, c3 = 0;
    if (base + 3 < N) {
        const int4 v = *(const int4*)(cnt + base);
        c0 = v.x; c1 = v.y; c2 = v.z; c3 = v.w;
    } else {
        if (base + 0 < N) c0 = cnt[base + 0];
        if (base + 1 < N) c1 = cnt[base + 1];
        if (base + 2 < N) c2 = cnt[base + 2];
        if (base + 3 < N) c3 = cnt[base + 3];
    }
    int ts = c0 + c1 + c2 + c3;
    sums[t] = ts;
    __syncthreads();
    for (int off = 1; off < 256; off <<= 1) {
        int v = (t >= off) ? sums[t - off] : 0;
        __syncthreads();
        sums[t] += v;
        __syncthreads();
    }
    int pre = sums[t] - ts;
    if (base + 0 < N) { rowptr[base + 0] = pre;                 dis[base + 0] = rsqrtf((float)c0 + 1.f); }
    if (base + 1 < N) { rowptr[base + 1] = pre + c0;            dis[base + 1] = rsqrtf((float)c1 + 1.f); }
    if (base + 2 < N) { rowptr[base + 2] = pre + c0 + c1;       dis[base + 2] = rsqrtf((float)c2 + 1.f); }
    if (base + 3 < N) { rowptr[base + 3] = pre + c0 + c1 + c2;  dis[base + 3] = rsqrtf((float)c3 + 1.f); }
    if (t == 255) bsum[blockIdx.x] = sums[255];
}

// ---- scan phase 2: exclusive prefix of block totals (B <= 256) ----
__global__ __launch_bounds__(256) void k_scan2(int* __restrict__ bsum, int B) {
    __shared__ int s[256];
    int t = threadIdx.x;
    int v = (t < B) ? bsum[t] : 0;
    s[t] = v;
    __syncthreads();
    for (int off = 1; off < 256; off <<= 1) {
        int u = (t >= off) ? s[t - off] : 0;
        __syncthreads();
        s[t] += u;
        __syncthreads();
    }
    if (t < B) bsum[t] = s[t] - v;
}

// ---- scan phase 3: add block offsets; materialize cursor; rowptr[N]=E ----
__global__ __launch_bounds__(256) void k_scan3(int* __restrict__ rowptr,
                                               int* __restrict__ cursor,
                                               const int* __restrict__ bsum, int N, int E) {
    int i = blockIdx.x * blockDim.x + threadIdx.x;
    if (i < N) {
        int v = rowptr[i] + bsum[i >> 10];
        rowptr[i] = v;
        cursor[i] = v;
    }
    if (i == 0) rowptr[N] = E;
}

// ---- embW1[p][c] = (emb @ W1)[p][c]   (512 x 128 x 128 — tiny) ----
__global__ void k_emb_matmul(const float* __restrict__ emb,
                             const float* __restrict__ W,
                             float* __restrict__ out) {
    int p = blockIdx.x;
    int c = threadIdx.x;
    float s = 0.f;
#pragma unroll 8
    for (int k = 0; k < DD; k++)
        s += emb[p * DD + k] * W[k * DD + c];
    out[p * DD + c] = s;
}

// ---- W2 -> bf16, pre-swizzled into MFMA B-fragment order ----
// Wb[((nt*4+ks)*64 + lane)*8 + j] = bf16( W2[(ks*32 + (lane>>4)*8 + j)*128 + nt*16 + (lane&15)] )
__global__ __launch_bounds__(256) void k_wconv(const float* __restrict__ W,
                                               unsigned short* __restrict__ Wb) {
    int t = blockIdx.x * blockDim.x + threadIdx.x;   // 0..2047: (nt, ks, lane)
    if (t >= 2048) return;
    int nt = t >> 8, ks = (t >> 6) & 3, lane = t & 63;
    int n = nt * 16 + (lane & 15);
    int kbase = ks * 32 + (lane >> 4) * 8;
    unsigned short* o = Wb + (size_t)t * 8;
#pragma unroll
    for (int j = 0; j < 8; j++)
        o[j] = f2bf(W[(kbase + j) * DD + n]);
}

// ---- bucket edges by dst: per-edge streams srcs / widx / disv ----
__global__ void k_bucket(const int* __restrict__ src, const int* __restrict__ dst,
                         const int* __restrict__ node_ids, const float* __restrict__ dis,
                         int* __restrict__ cursor, int* __restrict__ srcs,
                         int* __restrict__ widx, float* __restrict__ disv, int E) {
    int e = blockIdx.x * blockDim.x + threadIdx.x;
    if (e >= E) return;
    int s = src[e], d = dst[e];
    int pos = atomicAdd(&cursor[d], 1);
    srcs[pos] = s;
    widx[pos] = node_ids[s];
    disv[pos] = dis[s];
}

// ---- layer 1 fused: gather-reduce from embW1 + self-loop + bias + residual + LN -> x1 (f32) + x1b (bf16)
__global__ __launch_bounds__(256) void k_node1(const int* __restrict__ rowptr,
                                               const int* __restrict__ widx,
                                               const float* __restrict__ disv,
                                               const int* __restrict__ node_ids,
                                               const float* __restrict__ emb,
                                               const float* __restrict__ embW1,
                                               const float* __restrict__ dis,
                                               const float* __restrict__ b1,
                                               const float* __restrict__ g1,
                                               const float* __restrict__ beta1,
                                               float* __restrict__ x1,
                                               unsigned int* __restrict__ x1b, int N) {
    int i = (blockIdx.x * blockDim.x + threadIdx.x) >> 6;
    int lane = threadIdx.x & 63;
    if (i >= N) return;
    int r0 = rowptr[i], r1 = rowptr[i + 1];
    int c = lane * 2;
    float ax = 0.f, ay = 0.f;
    int j = r0;
    for (; j + 3 < r1; j += 4) {
        int p0 = widx[j], p1 = widx[j + 1], p2 = widx[j + 2], p3 = widx[j + 3];
        float n0 = disv[j], n1 = disv[j + 1], n2 = disv[j + 2], n3 = disv[j + 3];
        float2 a0 = *(const float2*)(embW1 + (size_t)p0 * DD + c);
        float2 a1 = *(const float2*)(embW1 + (size_t)p1 * DD + c);
        float2 a2 = *(const float2*)(embW1 + (size_t)p2 * DD + c);
        float2 a3 = *(const float2*)(embW1 + (size_t)p3 * DD + c);
        ax += a0.x * n0 + a1.x * n1 + a2.x * n2 + a3.x * n3;
        ay += a0.y * n0 + a1.y * n1 + a2.y * n2 + a3.y * n3;
    }
    for (; j < r1; j++) {
        int p = widx[j]; float n = disv[j];
        float2 a = *(const float2*)(embW1 + (size_t)p * DD + c);
        ax += a.x * n; ay += a.y * n;
    }
    float di = dis[i];
    int pid = node_ids[i];
    float2 ev = *(const float2*)(emb + (size_t)pid * DD + c);
    float2 hw = *(const float2*)(embW1 + (size_t)pid * DD + c);
    float v0 = ev.x + di * (ax + di * hw.x) + b1[c];
    float v1 = ev.y + di * (ay + di * hw.y) + b1[c + 1];
    float sum = v0 + v1;
#pragma unroll
    for (int o = 32; o >= 1; o >>= 1) sum += __shfl_xor(sum, o, 64);
    float mu = sum * (1.f / DD);
    float d0 = v0 - mu, d1 = v1 - mu;
    float ss = d0 * d0 + d1 * d1;
#pragma unroll
    for (int o = 32; o >= 1; o >>= 1) ss += __shfl_xor(ss, o, 64);
    float r = rsqrtf(ss * (1.f / DD) + 1e-5f);
    float o0 = d0 * r * g1[c] + beta1[c];
    float o1 = d1 * r * g1[c + 1] + beta1[c + 1];
    float2 outv; outv.x = o0; outv.y = o1;
    *(float2*)(x1 + (size_t)i * DD + c) = outv;
    x1b[(size_t)i * 64 + lane] = (unsigned)f2bf(o0) | ((unsigned)f2bf(o1) << 16);
}

// ---- h2s = (x1 @ W2) * dis[row]  via bf16 MFMA; one wave per 16-row strip ----
__global__ __launch_bounds__(256) void k_gemm_mfma(const unsigned short* __restrict__ x1b,
                                                   const unsigned short* __restrict__ Wb,
                                                   const float* __restrict__ dis,
                                                   float* __restrict__ h, int N) {
    int wave = (blockIdx.x * blockDim.x + threadIdx.x) >> 6;
    int lane = threadIdx.x & 63;
    int row0 = wave * 16;
    if (row0 >= N) return;
    int m = lane & 15, quad = lane >> 4;

    // A-fragments: a[ks][j] = x1[row0+m][ks*32 + quad*8 + j]
    short8 afr[4];
    const short8* ap = (const short8*)(x1b + (size_t)(row0 + m) * DD + quad * 8);
#pragma unroll
    for (int ks = 0; ks < 4; ks++) afr[ks] = ap[ks * 4];  // ks*32 shorts = 4 short8

    // dis for the 4 rows this lane's accumulators cover: row0 + quad*4 + r
    float4 dv = *(const float4*)(dis + row0 + quad * 4);
    float dr[4] = {dv.x, dv.y, dv.z, dv.w};

    const short8* bp = (const short8*)Wb + (size_t)lane;  // + (nt*4+ks)*64
#pragma unroll
    for (int nt = 0; nt < 8; nt++) {
        float4v acc = {0.f, 0.f, 0.f, 0.f};
#pragma unroll
        for (int ks = 0; ks < 4; ks++) {
            short8 bfr = bp[(nt * 4 + ks) * 64];
            acc = __builtin_amdgcn_mfma_f32_16x16x32_bf16(afr[ks], bfr, acc, 0, 0, 0);
        }
        int col = nt * 16 + m;
#pragma unroll
        for (int r = 0; r < 4; r++)
            h[(size_t)(row0 + quad * 4 + r) * DD + col] = acc[r] * dr[r];
    }
}

// ---- layer 2 fused: gather-reduce of pre-scaled h2s rows + self-loop + bias + residual + LN -> out
__global__ __launch_bounds__(256) void k_node2(const int* __restrict__ rowptr,
                                               const int* __restrict__ srcs,
                                               const float* __restrict__ x1,
                                               const float* __restrict__ h2s,
                                               const float* __restrict__ dis,
                                               const float* __restrict__ b2,
                                               const float* __restrict__ g2,
                                               const float* __restrict__ beta2,
                                               float* __restrict__ out, int N) {
    int i = (blockIdx.x * blockDim.x + threadIdx.x) >> 6;
    int lane = threadIdx.x & 63;
    if (i >= N) return;
    int r0 = rowptr[i], r1 = rowptr[i + 1];
    int c = lane * 2;
    float ax = 0.f, ay = 0.f;
    int j = r0;
    for (; j + 3 < r1; j += 4) {
        int s0 = srcs[j], s1 = srcs[j + 1], s2 = srcs[j + 2], s3 = srcs[j + 3];
        float2 a0 = *(const float2*)(h2s + (size_t)s0 * DD + c);
        float2 a1 = *(const float2*)(h2s + (size_t)s1 * DD + c);
        float2 a2 = *(const float2*)(h2s + (size_t)s2 * DD + c);
        float2 a3 = *(const float2*)(h2s + (size_t)s3 * DD + c);
        ax += a0.x + a1.x + a2.x + a3.x;
        ay += a0.y + a1.y + a2.y + a3.y;
    }
    for (; j < r1; j++) {
        int s = srcs[j];
        float2 a = *(const float2*)(h2s + (size_t)s * DD + c);
        ax += a.x; ay += a.y;
    }
    float di = dis[i];
    size_t ib = (size_t)i * DD + c;
    float2 xv = *(const float2*)(x1 + ib);
    float2 hv = *(const float2*)(h2s + ib);  // already scaled by dis[i]
    float v0 = xv.x + di * (ax + hv.x) + b2[c];
    float v1 = xv.y + di * (ay + hv.y) + b2[c + 1];
    float sum = v0 + v1;
#pragma unroll
    for (int o = 32; o >= 1; o >>= 1) sum += __shfl_xor(sum, o, 64);
    float mu = sum * (1.f / DD);
    float d0 = v0 - mu, d1 = v1 - mu;
    float ss = d0 * d0 + d1 * d1;
#pragma unroll
    for (int o = 32; o >= 1; o >>= 1) ss += __shfl_xor(ss, o, 64);
    float r = rsqrtf(ss * (1.f / DD) + 1e-5f);
    float2 outv;
    outv.x = d0 * r * g2[c] + beta2[c];
    outv.y = d1 * r * g2[c + 1] + beta2[c + 1];
    *(float2*)(out + ib) = outv;
}

extern "C" void kernel_launch(void* const* d_in, const int* in_sizes, int n_in,
                              void* d_out, int out_size, void* d_ws, size_t ws_size,
                              hipStream_t stream) {
    const int* node_ids = (const int*)d_in[0];
    const int* edge_index = (const int*)d_in[1];
    const float* emb   = (const float*)d_in[2];
    const float* W1    = (const float*)d_in[3];
    const float* b1    = (const float*)d_in[4];
    const float* W2    = (const float*)d_in[5];
    const float* b2    = (const float*)d_in[6];
    const float* g1    = (const float*)d_in[7];
    const float* beta1 = (const float*)d_in[8];
    const float* g2    = (const float*)d_in[9];
    const float* beta2 = (const float*)d_in[10];
    const int N = in_sizes[0];
    const int E = in_sizes[1] / 2;
    const int* srcp = edge_index;
    const int* dstp = edge_index + E;
    float* out = (float*)d_out;

    char* base = (char*)d_ws;
    size_t off = 0;
    auto carve = [&](size_t bytes) -> void* {
        void* p = base + off;
        off += (bytes + 255) & ~(size_t)255;
        return p;
    };
    int*   cnt    = (int*)carve((size_t)N * 4);
    int*   rowptr = (int*)carve((size_t)(N + 1) * 4);
    int*   cursor = (int*)carve((size_t)N * 4);
    float* dis    = (float*)carve((size_t)(N + 16) * 4);
    int*   bsum   = (int*)carve((size_t)256 * 4);
    int*   srcs   = (int*)carve((size_t)E * 4);
    int*   widx   = (int*)carve((size_t)E * 4);
    float* disv   = (float*)carve((size_t)E * 4);
    float* embW1  = (float*)carve((size_t)512 * DD * 4);
    float* x1     = (float*)carve((size_t)N * DD * 4);
    float* h2s    = (float*)carve((size_t)N * DD * 4);
    unsigned int*   x1b = (unsigned int*)carve((size_t)N * 64 * 4);
    unsigned short* Wb  = (unsigned short*)carve((size_t)DD * DD * 2);
    (void)ws_size; (void)n_in; (void)out_size;

    const int TB = 256;
    const int B = (N + 1023) / 1024;
    hipMemsetAsync(cnt, 0, (size_t)N * 4, stream);

    k_hist<<<(E + TB - 1) / TB, TB, 0, stream>>>(dstp, cnt, E);
    k_scan1<<<B, 256, 0, stream>>>(cnt, rowptr, dis, bsum, N);
    k_scan2<<<1, 256, 0, stream>>>(bsum, B);
    k_scan3<<<(N + TB - 1) / TB, TB, 0, stream>>>(rowptr, cursor, bsum, N, E);
    k_emb_matmul<<<512, DD, 0, stream>>>(emb, W1, embW1);
    k_wconv<<<8, 256, 0, stream>>>(W2, Wb);
    k_bucket<<<(E + TB - 1) / TB, TB, 0, stream>>>(srcp, dstp, node_ids, dis, cursor,
                                                   srcs, widx, disv, E);

    int nodeBlocks = (N * 64 + TB - 1) / TB;
    k_node1<<<nodeBlocks, TB, 0, stream>>>(rowptr, widx, disv, node_ids, emb, embW1, dis,
                                           b1, g1, beta1, x1, x1b, N);
    int waves = (N + 15) / 16;                       // one wave per 16 rows
    int gb = (waves + 3) / 4;                        // 4 waves per block
    k_gemm_mfma<<<gb, 256, 0, stream>>>((const unsigned short*)x1b, Wb, dis, h2s, N);
    k_node2<<<nodeBlocks, TB, 0, stream>>>(rowptr, srcs, x1, h2s, dis,
                                           b2, g2, beta2, out, N);
}

// Round 6
// 226.483 us; speedup vs baseline: 2.9133x; 1.0962x over previous
//
#include <hip/hip_runtime.h>

#define DD 128

typedef __attribute__((ext_vector_type(8))) short short8;
typedef __attribute__((ext_vector_type(4))) float float4v;

static __device__ __forceinline__ unsigned short f2bf(float x) {
    unsigned u = __builtin_bit_cast(unsigned, x);
    u += 0x7fffu + ((u >> 16) & 1u);   // RNE
    return (unsigned short)(u >> 16);
}
static __device__ __forceinline__ float bflo(unsigned u) {   // low bf16 -> float
    return __builtin_bit_cast(float, u << 16);
}
static __device__ __forceinline__ float bfhi(unsigned u) {   // high bf16 -> float
    return __builtin_bit_cast(float, u & 0xffff0000u);
}

// ---- in-degree histogram (int) ----
__global__ void k_hist(const int* __restrict__ dst, int* __restrict__ cnt, int E) {
    int e = blockIdx.x * blockDim.x + threadIdx.x;
    if (e < E) atomicAdd(&cnt[dst[e]], 1);
}

// ---- scan phase 1: per-block (1024-elem tile) exclusive prefix + block totals + dis ----
__global__ __launch_bounds__(256) void k_scan1(const int* __restrict__ cnt,
                                               int* __restrict__ rowptr,
                                               float* __restrict__ dis,
                                               int* __restrict__ bsum, int N) {
    __shared__ int sums[256];
    int t = threadIdx.x;
    int base = blockIdx.x * 1024 + t * 4;
    int c0 = 0, c1 = 0, c2 = 0, c3 = 0;
    if (base + 3 < N) {
        const int4 v = *(const int4*)(cnt + base);
        c0 = v.x; c1 = v.y; c2 = v.z; c3 = v.w;
    } else {
        if (base + 0 < N) c0 = cnt[base + 0];
        if (base + 1 < N) c1 = cnt[base + 1];
        if (base + 2 < N) c2 = cnt[base + 2];
        if (base + 3 < N) c3 = cnt[base + 3];
    }
    int ts = c0 + c1 + c2 + c3;
    sums[t] = ts;
    __syncthreads();
    for (int off = 1; off < 256; off <<= 1) {
        int v = (t >= off) ? sums[t - off] : 0;
        __syncthreads();
        sums[t] += v;
        __syncthreads();
    }
    int pre = sums[t] - ts;
    if (base + 0 < N) { rowptr[base + 0] = pre;                 dis[base + 0] = rsqrtf((float)c0 + 1.f); }
    if (base + 1 < N) { rowptr[base + 1] = pre + c0;            dis[base + 1] = rsqrtf((float)c1 + 1.f); }
    if (base + 2 < N) { rowptr[base + 2] = pre + c0 + c1;       dis[base + 2] = rsqrtf((float)c2 + 1.f); }
    if (base + 3 < N) { rowptr[base + 3] = pre + c0 + c1 + c2;  dis[base + 3] = rsqrtf((float)c3 + 1.f); }
    if (t == 255) bsum[blockIdx.x] = sums[255];
}

// ---- scan phase 2: exclusive prefix of block totals (B <= 256) ----
__global__ __launch_bounds__(256) void k_scan2(int* __restrict__ bsum, int B) {
    __shared__ int s[256];
    int t = threadIdx.x;
    int v = (t < B) ? bsum[t] : 0;
    s[t] = v;
    __syncthreads();
    for (int off = 1; off < 256; off <<= 1) {
        int u = (t >= off) ? s[t - off] : 0;
        __syncthreads();
        s[t] += u;
        __syncthreads();
    }
    if (t < B) bsum[t] = s[t] - v;
}

// ---- scan phase 3: add block offsets; materialize cursor; rowptr[N]=E ----
__global__ __launch_bounds__(256) void k_scan3(int* __restrict__ rowptr,
                                               int* __restrict__ cursor,
                                               const int* __restrict__ bsum, int N, int E) {
    int i = blockIdx.x * blockDim.x + threadIdx.x;
    if (i < N) {
        int v = rowptr[i] + bsum[i >> 10];
        rowptr[i] = v;
        cursor[i] = v;
    }
    if (i == 0) rowptr[N] = E;
}

// ---- embW1b[p] = bf16x2-packed (emb @ W1)[p]   (512 x 128 x 128 — tiny) ----
__global__ __launch_bounds__(64) void k_emb_matmul(const float* __restrict__ emb,
                                                   const float* __restrict__ W,
                                                   unsigned* __restrict__ outb) {
    int p = blockIdx.x;       // 512
    int t = threadIdx.x;      // 64: channel pair
    int c0 = t * 2, c1 = t * 2 + 1;
    float s0 = 0.f, s1 = 0.f;
#pragma unroll 8
    for (int k = 0; k < DD; k++) {
        float e = emb[p * DD + k];
        s0 += e * W[k * DD + c0];
        s1 += e * W[k * DD + c1];
    }
    outb[p * 64 + t] = (unsigned)f2bf(s0) | ((unsigned)f2bf(s1) << 16);
}

// ---- W2 -> bf16, pre-swizzled into MFMA B-fragment order ----
__global__ __launch_bounds__(256) void k_wconv(const float* __restrict__ W,
                                               unsigned short* __restrict__ Wb) {
    int t = blockIdx.x * blockDim.x + threadIdx.x;   // 0..2047: (nt, ks, lane)
    if (t >= 2048) return;
    int nt = t >> 8, ks = (t >> 6) & 3, lane = t & 63;
    int n = nt * 16 + (lane & 15);
    int kbase = ks * 32 + (lane >> 4) * 8;
    unsigned short* o = Wb + (size_t)t * 8;
#pragma unroll
    for (int j = 0; j < 8; j++)
        o[j] = f2bf(W[(kbase + j) * DD + n]);
}

// ---- bucket edges by dst: single per-edge stream srcs ----
__global__ void k_bucket(const int* __restrict__ src, const int* __restrict__ dst,
                         int* __restrict__ cursor, int* __restrict__ srcs, int E) {
    int e = blockIdx.x * blockDim.x + threadIdx.x;
    if (e >= E) return;
    int s = src[e], d = dst[e];
    int pos = atomicAdd(&cursor[d], 1);
    srcs[pos] = s;
}

// ---- layer 1 fused: gather-reduce from bf16 embW1 table + self-loop + bias + residual + LN -> x1b (bf16)
__global__ __launch_bounds__(256) void k_node1(const int* __restrict__ rowptr,
                                               const int* __restrict__ srcs,
                                               const int* __restrict__ node_ids,
                                               const float* __restrict__ emb,
                                               const unsigned* __restrict__ embW1b,
                                               const float* __restrict__ dis,
                                               const float* __restrict__ b1,
                                               const float* __restrict__ g1,
                                               const float* __restrict__ beta1,
                                               unsigned* __restrict__ x1b, int N) {
    int i = (blockIdx.x * blockDim.x + threadIdx.x) >> 6;
    int lane = threadIdx.x & 63;
    if (i >= N) return;
    int r0 = rowptr[i], r1 = rowptr[i + 1];
    int c = lane * 2;
    float ax = 0.f, ay = 0.f;
    int j = r0;
    for (; j + 3 < r1; j += 4) {
        int s0 = srcs[j], s1 = srcs[j + 1], s2 = srcs[j + 2], s3 = srcs[j + 3];
        float n0 = dis[s0], n1 = dis[s1], n2 = dis[s2], n3 = dis[s3];
        int p0 = node_ids[s0], p1 = node_ids[s1], p2 = node_ids[s2], p3 = node_ids[s3];
        unsigned a0 = embW1b[p0 * 64 + lane];
        unsigned a1 = embW1b[p1 * 64 + lane];
        unsigned a2 = embW1b[p2 * 64 + lane];
        unsigned a3 = embW1b[p3 * 64 + lane];
        ax += bflo(a0) * n0 + bflo(a1) * n1 + bflo(a2) * n2 + bflo(a3) * n3;
        ay += bfhi(a0) * n0 + bfhi(a1) * n1 + bfhi(a2) * n2 + bfhi(a3) * n3;
    }
    for (; j < r1; j++) {
        int s = srcs[j];
        float n = dis[s];
        unsigned a = embW1b[node_ids[s] * 64 + lane];
        ax += bflo(a) * n; ay += bfhi(a) * n;
    }
    float di = dis[i];
    int pid = node_ids[i];
    float2 ev = *(const float2*)(emb + (size_t)pid * DD + c);
    unsigned hw = embW1b[pid * 64 + lane];
    float v0 = ev.x + di * (ax + di * bflo(hw)) + b1[c];
    float v1 = ev.y + di * (ay + di * bfhi(hw)) + b1[c + 1];
    float sum = v0 + v1;
#pragma unroll
    for (int o = 32; o >= 1; o >>= 1) sum += __shfl_xor(sum, o, 64);
    float mu = sum * (1.f / DD);
    float d0 = v0 - mu, d1 = v1 - mu;
    float ss = d0 * d0 + d1 * d1;
#pragma unroll
    for (int o = 32; o >= 1; o >>= 1) ss += __shfl_xor(ss, o, 64);
    float r = rsqrtf(ss * (1.f / DD) + 1e-5f);
    float o0 = d0 * r * g1[c] + beta1[c];
    float o1 = d1 * r * g1[c + 1] + beta1[c + 1];
    x1b[(size_t)i * 64 + lane] = (unsigned)f2bf(o0) | ((unsigned)f2bf(o1) << 16);
}

// ---- h2b = bf16( (x1 @ W2) * dis[row] )  via bf16 MFMA; one wave per 16-row strip ----
__global__ __launch_bounds__(256) void k_gemm_mfma(const unsigned short* __restrict__ x1b,
                                                   const unsigned short* __restrict__ Wb,
                                                   const float* __restrict__ dis,
                                                   unsigned short* __restrict__ hb, int N) {
    int wave = (blockIdx.x * blockDim.x + threadIdx.x) >> 6;
    int lane = threadIdx.x & 63;
    int row0 = wave * 16;
    if (row0 >= N) return;
    int m = lane & 15, quad = lane >> 4;

    short8 afr[4];
    const short8* ap = (const short8*)(x1b + (size_t)(row0 + m) * DD + quad * 8);
#pragma unroll
    for (int ks = 0; ks < 4; ks++) afr[ks] = ap[ks * 4];

    float4 dv = *(const float4*)(dis + row0 + quad * 4);
    float dr[4] = {dv.x, dv.y, dv.z, dv.w};

    const short8* bp = (const short8*)Wb + (size_t)lane;
#pragma unroll
    for (int nt = 0; nt < 8; nt++) {
        float4v acc = {0.f, 0.f, 0.f, 0.f};
#pragma unroll
        for (int ks = 0; ks < 4; ks++) {
            short8 bfr = bp[(nt * 4 + ks) * 64];
            acc = __builtin_amdgcn_mfma_f32_16x16x32_bf16(afr[ks], bfr, acc, 0, 0, 0);
        }
        int col = nt * 16 + m;
#pragma unroll
        for (int r = 0; r < 4; r++) {
            int row = row0 + quad * 4 + r;
            if (row < N) hb[(size_t)row * DD + col] = f2bf(acc[r] * dr[r]);
        }
    }
}

// ---- layer 2 fused: gather-reduce of bf16 pre-scaled h2 rows + self-loop + bias + residual + LN -> out
__global__ __launch_bounds__(256) void k_node2(const int* __restrict__ rowptr,
                                               const int* __restrict__ srcs,
                                               const unsigned* __restrict__ x1b,
                                               const unsigned* __restrict__ h2b,
                                               const float* __restrict__ dis,
                                               const float* __restrict__ b2,
                                               const float* __restrict__ g2,
                                               const float* __restrict__ beta2,
                                               float* __restrict__ out, int N) {
    int i = (blockIdx.x * blockDim.x + threadIdx.x) >> 6;
    int lane = threadIdx.x & 63;
    if (i >= N) return;
    int r0 = rowptr[i], r1 = rowptr[i + 1];
    int c = lane * 2;
    float ax = 0.f, ay = 0.f;
    int j = r0;
    for (; j + 3 < r1; j += 4) {
        int s0 = srcs[j], s1 = srcs[j + 1], s2 = srcs[j + 2], s3 = srcs[j + 3];
        unsigned a0 = h2b[(size_t)s0 * 64 + lane];
        unsigned a1 = h2b[(size_t)s1 * 64 + lane];
        unsigned a2 = h2b[(size_t)s2 * 64 + lane];
        unsigned a3 = h2b[(size_t)s3 * 64 + lane];
        ax += bflo(a0) + bflo(a1) + bflo(a2) + bflo(a3);
        ay += bfhi(a0) + bfhi(a1) + bfhi(a2) + bfhi(a3);
    }
    for (; j < r1; j++) {
        unsigned a = h2b[(size_t)srcs[j] * 64 + lane];
        ax += bflo(a); ay += bfhi(a);
    }
    float di = dis[i];
    unsigned xv = x1b[(size_t)i * 64 + lane];
    unsigned hv = h2b[(size_t)i * 64 + lane];   // already scaled by dis[i]
    float v0 = bflo(xv) + di * (ax + bflo(hv)) + b2[c];
    float v1 = bfhi(xv) + di * (ay + bfhi(hv)) + b2[c + 1];
    float sum = v0 + v1;
#pragma unroll
    for (int o = 32; o >= 1; o >>= 1) sum += __shfl_xor(sum, o, 64);
    float mu = sum * (1.f / DD);
    float d0 = v0 - mu, d1 = v1 - mu;
    float ss = d0 * d0 + d1 * d1;
#pragma unroll
    for (int o = 32; o >= 1; o >>= 1) ss += __shfl_xor(ss, o, 64);
    float r = rsqrtf(ss * (1.f / DD) + 1e-5f);
    float2 outv;
    outv.x = d0 * r * g2[c] + beta2[c];
    outv.y = d1 * r * g2[c + 1] + beta2[c + 1];
    *(float2*)(out + (size_t)i * DD + c) = outv;
}

extern "C" void kernel_launch(void* const* d_in, const int* in_sizes, int n_in,
                              void* d_out, int out_size, void* d_ws, size_t ws_size,
                              hipStream_t stream) {
    const int* node_ids = (const int*)d_in[0];
    const int* edge_index = (const int*)d_in[1];
    const float* emb   = (const float*)d_in[2];
    const float* W1    = (const float*)d_in[3];
    const float* b1    = (const float*)d_in[4];
    const float* W2    = (const float*)d_in[5];
    const float* b2    = (const float*)d_in[6];
    const float* g1    = (const float*)d_in[7];
    const float* beta1 = (const float*)d_in[8];
    const float* g2    = (const float*)d_in[9];
    const float* beta2 = (const float*)d_in[10];
    const int N = in_sizes[0];
    const int E = in_sizes[1] / 2;
    const int* srcp = edge_index;
    const int* dstp = edge_index + E;
    float* out = (float*)d_out;

    char* base = (char*)d_ws;
    size_t off = 0;
    auto carve = [&](size_t bytes) -> void* {
        void* p = base + off;
        off += (bytes + 255) & ~(size_t)255;
        return p;
    };
    int*      cnt    = (int*)carve((size_t)N * 4);
    int*      rowptr = (int*)carve((size_t)(N + 1) * 4);
    int*      cursor = (int*)carve((size_t)N * 4);
    float*    dis    = (float*)carve((size_t)(N + 16) * 4);
    int*      bsum   = (int*)carve((size_t)256 * 4);
    int*      srcs   = (int*)carve((size_t)E * 4);
    unsigned* embW1b = (unsigned*)carve((size_t)512 * 64 * 4);
    unsigned* x1b    = (unsigned*)carve((size_t)(N + 16) * 64 * 4);
    unsigned* h2b    = (unsigned*)carve((size_t)(N + 16) * 64 * 4);
    unsigned short* Wb = (unsigned short*)carve((size_t)DD * DD * 2);
    (void)ws_size; (void)n_in; (void)out_size;

    const int TB = 256;
    const int B = (N + 1023) / 1024;
    hipMemsetAsync(cnt, 0, (size_t)N * 4, stream);

    k_hist<<<(E + TB - 1) / TB, TB, 0, stream>>>(dstp, cnt, E);
    k_scan1<<<B, 256, 0, stream>>>(cnt, rowptr, dis, bsum, N);
    k_scan2<<<1, 256, 0, stream>>>(bsum, B);
    k_scan3<<<(N + TB - 1) / TB, TB, 0, stream>>>(rowptr, cursor, bsum, N, E);
    k_emb_matmul<<<512, 64, 0, stream>>>(emb, W1, embW1b);
    k_wconv<<<8, 256, 0, stream>>>(W2, Wb);
    k_bucket<<<(E + TB - 1) / TB, TB, 0, stream>>>(srcp, dstp, cursor, srcs, E);

    int nodeBlocks = (N * 64 + TB - 1) / TB;
    k_node1<<<nodeBlocks, TB, 0, stream>>>(rowptr, srcs, node_ids, emb, embW1b, dis,
                                           b1, g1, beta1, x1b, N);
    int waves = (N + 15) / 16;
    int gb = (waves + 3) / 4;
    k_gemm_mfma<<<gb, 256, 0, stream>>>((const unsigned short*)x1b, Wb, dis,
                                        (unsigned short*)h2b, N);
    k_node2<<<nodeBlocks, TB, 0, stream>>>(rowptr, srcs, x1b, h2b, dis,
                                           b2, g2, beta2, out, N);
}